// Round 4
// baseline (542.681 us; speedup 1.0000x reference)
//
#include <hip/hip_runtime.h>

#define NN 50000
#define NE 600000
#define FIN 64
#define FHID 128
#define BN_EPS 1e-5f
#define CAP 64

typedef __attribute__((ext_vector_type(8))) short short8;
typedef __attribute__((ext_vector_type(4))) float f32x4;

// ---- bf16 helpers (finite inputs; RNE) ----
__device__ __forceinline__ unsigned short f2bf(float f) {
  unsigned u = __float_as_uint(f);
  return (unsigned short)((u + 0x7FFFu + ((u >> 16) & 1u)) >> 16);
}
__device__ __forceinline__ float bfs(unsigned short u) {
  return __uint_as_float(((unsigned)u) << 16);
}
__device__ __forceinline__ float bflo(unsigned v) { return __uint_as_float(v << 16); }
__device__ __forceinline__ float bfhi(unsigned v) { return __uint_as_float(v & 0xFFFF0000u); }
__device__ __forceinline__ unsigned pk2(float lo, float hi) {
  return (unsigned)f2bf(lo) | ((unsigned)f2bf(hi) << 16);
}

// ---- device-scope grid barrier (all blocks co-resident by construction) ----
// Compiler drains vmcnt before s_barrier, so t0's fence covers the block's
// stores (L1 per CU, L2 per XCD). Release: writeback; Acquire: invalidate.
__device__ __forceinline__ void gridbar(int* ctr, int target) {
  __syncthreads();
  if (threadIdx.x == 0) {
    __threadfence();  // release: push this XCD's dirty lines to coherent point
    __hip_atomic_fetch_add(ctr, 1, __ATOMIC_ACQ_REL, __HIP_MEMORY_SCOPE_AGENT);
    while (__hip_atomic_load(ctr, __ATOMIC_ACQUIRE, __HIP_MEMORY_SCOPE_AGENT) <
           target)
      __builtin_amdgcn_s_sleep(4);
    __threadfence();  // acquire: invalidate stale lines for this CU/XCD
  }
  __syncthreads();
}

// ---------------- fused: bucket CSR build -> scale_x+pad -> gcn_agg ---------
// 768 blocks x 256 thr @ 4 blocks/CU guaranteed (needs 192 of 256 CUs).
__device__ __forceinline__ void gacc(float& a0, float& a1, float& a2, float& a3,
                                     ushort4 v) {
  a0 += bfs(v.x); a1 += bfs(v.y); a2 += bfs(v.z); a3 += bfs(v.w);
}

__global__ __launch_bounds__(256, 4) void fused_pre(
    const int* __restrict__ src, const int* __restrict__ dst,
    const float* __restrict__ x, int* __restrict__ cnt, int* __restrict__ csr,
    ushort4* __restrict__ xs, unsigned short* __restrict__ xa,
    int* __restrict__ bar) {
  int tid = threadIdx.x;
  int gtid = blockIdx.x * 256 + tid;
  int gstride = gridDim.x * 256;

  // ---- phase 1: bucketed CSR fill (cnt zeroed by host memset) ----
  for (int e4 = gtid; e4 < NE / 4; e4 += gstride) {
    int4 d4 = ((const int4*)dst)[e4];
    int4 s4 = ((const int4*)src)[e4];
    int p;
    p = atomicAdd(&cnt[d4.x], 1); if (p < CAP) csr[(size_t)d4.x * CAP + p] = s4.x;
    p = atomicAdd(&cnt[d4.y], 1); if (p < CAP) csr[(size_t)d4.y * CAP + p] = s4.y;
    p = atomicAdd(&cnt[d4.z], 1); if (p < CAP) csr[(size_t)d4.z * CAP + p] = s4.z;
    p = atomicAdd(&cnt[d4.w], 1); if (p < CAP) csr[(size_t)d4.w * CAP + p] = s4.w;
  }
  gridbar(bar + 0, gridDim.x);

  // ---- phase 2: xs = dis*x (fp32->bf16), pad buckets to multiple of 8 ----
  for (int i = gtid; i < NN * FIN / 4; i += gstride) {
    float4 v = ((const float4*)x)[i];
    int node = i >> 4;
    float d = rsqrtf((float)(cnt[node] + 1));
    xs[i] = make_ushort4(f2bf(v.x * d), f2bf(v.y * d), f2bf(v.z * d), f2bf(v.w * d));
    if (i < NN) {
      int deg = min(cnt[i], CAP);
      int deg8 = (deg + 7) & ~7;
      int* cb = csr + (size_t)i * CAP;
      for (int p = deg; p < deg8; ++p) cb[p] = 0;
    }
  }
  gridbar(bar + 1, gridDim.x);

  // ---- phase 3: GCN aggregation (16-lane groups, branchless padded) ----
  {
    const unsigned short* xsu = (const unsigned short*)xs;
    int li = tid & 15;
    int g0 = blockIdx.x * 16 + (tid >> 4);
    int ngroups = gridDim.x * 16;
    ushort4 zv = *(const ushort4*)(xsu + li * 4);  // row 0 (pad target)
    for (int node = g0; node < NN; node += ngroups) {
      int degr = cnt[node];
      int deg = min(degr, CAP);
      int deg8 = (deg + 7) & ~7;
      float di = rsqrtf((float)(degr + 1));
      ushort4 sv = *(const ushort4*)(xsu + (size_t)node * FIN + li * 4);
      float a0 = bfs(sv.x), a1 = bfs(sv.y), a2 = bfs(sv.z), a3 = bfs(sv.w);
      const int* cb = csr + (size_t)node * CAP;
      int4 sA = *(const int4*)(cb);
      int4 sB = *(const int4*)(cb + 4);
      for (int e = 0; e < deg8; e += 8) {
        int pn = min(e + 8, CAP - 8);
        int4 nA = *(const int4*)(cb + pn);
        int4 nB = *(const int4*)(cb + pn + 4);
        ushort4 v0 = *(const ushort4*)(xsu + (size_t)sA.x * FIN + li * 4);
        ushort4 v1 = *(const ushort4*)(xsu + (size_t)sA.y * FIN + li * 4);
        ushort4 v2 = *(const ushort4*)(xsu + (size_t)sA.z * FIN + li * 4);
        ushort4 v3 = *(const ushort4*)(xsu + (size_t)sA.w * FIN + li * 4);
        ushort4 v4 = *(const ushort4*)(xsu + (size_t)sB.x * FIN + li * 4);
        ushort4 v5 = *(const ushort4*)(xsu + (size_t)sB.y * FIN + li * 4);
        ushort4 v6 = *(const ushort4*)(xsu + (size_t)sB.z * FIN + li * 4);
        ushort4 v7 = *(const ushort4*)(xsu + (size_t)sB.w * FIN + li * 4);
        gacc(a0, a1, a2, a3, v0); gacc(a0, a1, a2, a3, v1);
        gacc(a0, a1, a2, a3, v2); gacc(a0, a1, a2, a3, v3);
        gacc(a0, a1, a2, a3, v4); gacc(a0, a1, a2, a3, v5);
        gacc(a0, a1, a2, a3, v6); gacc(a0, a1, a2, a3, v7);
        sA = nA; sB = nB;
      }
      float pc = (float)(deg8 - deg);  // pads gathered row 0
      a0 -= pc * bfs(zv.x); a1 -= pc * bfs(zv.y);
      a2 -= pc * bfs(zv.z); a3 -= pc * bfs(zv.w);
      ushort4 o = make_ushort4(f2bf(di * a0), f2bf(di * a1), f2bf(di * a2),
                               f2bf(di * a3));
      *(ushort4*)(xa + (size_t)node * FIN + li * 4) = o;
    }
  }
}

// ---------------- SAGE mean aggregation on bf16 h (128 feats) ---------------
__device__ __forceinline__ void sacc(float* a, uint4 v) {
  a[0] += bflo(v.x); a[1] += bfhi(v.x);
  a[2] += bflo(v.y); a[3] += bfhi(v.y);
  a[4] += bflo(v.z); a[5] += bfhi(v.z);
  a[6] += bflo(v.w); a[7] += bfhi(v.w);
}

__global__ __launch_bounds__(256) void sage_agg(const unsigned* __restrict__ hb,
                                                const int* __restrict__ csr,
                                                const int* __restrict__ cnt,
                                                unsigned* __restrict__ neighb) {
  int tid = threadIdx.x;
  int node = blockIdx.x * 16 + (tid >> 4);
  int li = tid & 15;
  int degr = cnt[node];
  int deg = min(degr, CAP);
  int deg8 = (deg + 7) & ~7;
  float a[8];
#pragma unroll
  for (int i = 0; i < 8; ++i) a[i] = 0.f;
  uint4 zv = *(const uint4*)(hb + li * 4);  // row 0 (pad target)
  const int* cb = csr + (size_t)node * CAP;
  int4 sA = *(const int4*)(cb);
  int4 sB = *(const int4*)(cb + 4);
  for (int e = 0; e < deg8; e += 8) {
    int pn = min(e + 8, CAP - 8);
    int4 nA = *(const int4*)(cb + pn);
    int4 nB = *(const int4*)(cb + pn + 4);
    uint4 v0 = *(const uint4*)(hb + (size_t)sA.x * 64 + li * 4);
    uint4 v1 = *(const uint4*)(hb + (size_t)sA.y * 64 + li * 4);
    uint4 v2 = *(const uint4*)(hb + (size_t)sA.z * 64 + li * 4);
    uint4 v3 = *(const uint4*)(hb + (size_t)sA.w * 64 + li * 4);
    uint4 v4 = *(const uint4*)(hb + (size_t)sB.x * 64 + li * 4);
    uint4 v5 = *(const uint4*)(hb + (size_t)sB.y * 64 + li * 4);
    uint4 v6 = *(const uint4*)(hb + (size_t)sB.z * 64 + li * 4);
    uint4 v7 = *(const uint4*)(hb + (size_t)sB.w * 64 + li * 4);
    sacc(a, v0); sacc(a, v1); sacc(a, v2); sacc(a, v3);
    sacc(a, v4); sacc(a, v5); sacc(a, v6); sacc(a, v7);
    sA = nA; sB = nB;
  }
  float pc = (float)(deg8 - deg);
  a[0] -= pc * bflo(zv.x); a[1] -= pc * bfhi(zv.x);
  a[2] -= pc * bflo(zv.y); a[3] -= pc * bfhi(zv.y);
  a[4] -= pc * bflo(zv.z); a[5] -= pc * bfhi(zv.z);
  a[6] -= pc * bflo(zv.w); a[7] -= pc * bfhi(zv.w);
  float inv = 1.0f / fmaxf((float)degr, 1.0f);
  uint4 o;
  o.x = pk2(a[0] * inv, a[1] * inv);
  o.y = pk2(a[2] * inv, a[3] * inv);
  o.z = pk2(a[4] * inv, a[5] * inv);
  o.w = pk2(a[6] * inv, a[7] * inv);
  *(uint4*)(neighb + (size_t)node * 64 + li * 4) = o;
}

// -------- MFMA bf16 GEMM + bias + BN stats + grid barrier + BN apply --------
// 391 blocks @ 2 blocks/CU guaranteed (needs 196 of 256 CUs). acc stays in
// registers across the barrier; output stored once, post-BN+ReLU.
template <int K1, int K2, bool OUTBF>
__global__ __launch_bounds__(256, 2) void gemm_bn(
    const short* __restrict__ A1, const short* __restrict__ A2,
    const float* __restrict__ B1, const float* __restrict__ B2,
    const float* __restrict__ bias, float* __restrict__ Cf,
    unsigned short* __restrict__ Cb, float* __restrict__ sums,
    float* __restrict__ sumsq, const float* __restrict__ gamma,
    const float* __restrict__ beta, int* __restrict__ bar, int nblk) {
  constexpr int KT = K1 + K2;
  constexpr int NK1 = K1 / 32;
  constexpr int NKS = KT / 32;
  __shared__ short Bp[8 * NKS * 64 * 8];  // 64KB (KT=256) / 16KB (KT=64)
  __shared__ float lsum[128], lsq[128];   // stats, then reused as sc/sh
  int tid = threadIdx.x;
  if (tid < 128) { lsum[tid] = 0.f; lsq[tid] = 0.f; }
  // stage B: float4 global loads, scatter to fragment-linear LDS
  for (int idx = tid; idx < KT * 32; idx += 256) {
    int k = idx >> 5, c4 = idx & 31;
    const float* Bsrc = (K2 == 0 || k < K1) ? (B1 + k * 128) : (B2 + (k - K1) * 128);
    float4 wv = *(const float4*)(Bsrc + c4 * 4);
    int ks = k >> 5, q = (k >> 3) & 3, kk = k & 7;
#pragma unroll
    for (int j = 0; j < 4; ++j) {
      int c = c4 * 4 + j;
      int nf = c >> 4, r = c & 15;
      float wj = j == 0 ? wv.x : (j == 1 ? wv.y : (j == 2 ? wv.z : wv.w));
      Bp[((nf * NKS + ks) * 64 + q * 16 + r) * 8 + kk] = (short)f2bf(wj);
    }
  }
  __syncthreads();

  int lane = tid & 63;
  int w = tid >> 6;
  int r = lane & 15;
  int q = lane >> 4;
  int row_base = blockIdx.x * 128 + w * 32;
  int row0 = row_base + r;
  int row1 = row_base + 16 + r;
  row0 = row0 < NN ? row0 : NN - 1;  // clamp: garbage rows never stored
  row1 = row1 < NN ? row1 : NN - 1;

  // prefetch all A fragments (independent loads -> single latency exposure)
  short8 af[2][NKS];
#pragma unroll
  for (int ks = 0; ks < NKS; ++ks) {
    const short* A = (K2 == 0 || ks < NK1) ? A1 : A2;
    const int Kw = (K2 == 0 || ks < NK1) ? K1 : K2;
    const int ko = ((K2 == 0 || ks < NK1) ? ks : ks - NK1) * 32;
    af[0][ks] = *(const short8*)(A + (size_t)row0 * Kw + ko + q * 8);
    af[1][ks] = *(const short8*)(A + (size_t)row1 * Kw + ko + q * 8);
  }

  f32x4 acc[2][8];
#pragma unroll
  for (int m = 0; m < 2; ++m)
#pragma unroll
    for (int n = 0; n < 8; ++n) acc[m][n] = (f32x4){0.f, 0.f, 0.f, 0.f};

#pragma unroll
  for (int ks = 0; ks < NKS; ++ks) {
#pragma unroll
    for (int n = 0; n < 8; ++n) {
      short8 bf = *(const short8*)(Bp + ((size_t)(n * NKS + ks) * 64 + lane) * 8);
      acc[0][n] = __builtin_amdgcn_mfma_f32_16x16x32_bf16(af[0][ks], bf, acc[0][n], 0, 0, 0);
      acc[1][n] = __builtin_amdgcn_mfma_f32_16x16x32_bf16(af[1][ks], bf, acc[1][n], 0, 0, 0);
    }
  }

  // bias + per-thread column stats (pre-BN values kept in acc)
  float bias_r[8];
#pragma unroll
  for (int n = 0; n < 8; ++n) bias_r[n] = bias[n * 16 + r];
  float cs[8], cq[8];
#pragma unroll
  for (int n = 0; n < 8; ++n) { cs[n] = 0.f; cq[n] = 0.f; }
#pragma unroll
  for (int m = 0; m < 2; ++m)
#pragma unroll
    for (int i = 0; i < 4; ++i) {
      int row = row_base + m * 16 + q * 4 + i;
      if (row < NN) {
#pragma unroll
        for (int n = 0; n < 8; ++n) {
          float v = acc[m][n][i] + bias_r[n];
          acc[m][n][i] = v;
          cs[n] += v;
          cq[n] += v * v;
        }
      }
    }
#pragma unroll
  for (int n = 0; n < 8; ++n) {
    atomicAdd(&lsum[n * 16 + r], cs[n]);
    atomicAdd(&lsq[n * 16 + r], cq[n]);
  }
  __syncthreads();
  if (tid < 128) {
    atomicAdd(&sums[tid], lsum[tid]);
    atomicAdd(&sumsq[tid], lsq[tid]);
  }

  gridbar(bar, nblk);  // stats complete grid-wide

  if (tid < 128) {
    float mean = sums[tid] * (1.0f / NN);
    float var = fmaxf(sumsq[tid] * (1.0f / NN) - mean * mean, 0.f);
    float inv = rsqrtf(var + BN_EPS);
    float s = gamma[tid] * inv;
    lsum[tid] = s;                      // sc
    lsq[tid] = beta[tid] - mean * s;    // sh
  }
  __syncthreads();

#pragma unroll
  for (int m = 0; m < 2; ++m)
#pragma unroll
    for (int i = 0; i < 4; ++i) {
      int row = row_base + m * 16 + q * 4 + i;
      if (row < NN) {
#pragma unroll
        for (int n = 0; n < 8; ++n) {
          int col = n * 16 + r;
          float o = fmaxf(fmaf(acc[m][n][i], lsum[col], lsq[col]), 0.f);
          if constexpr (OUTBF)
            Cb[(size_t)row * 128 + col] = f2bf(o);
          else
            Cf[(size_t)row * 128 + col] = o;
        }
      }
    }
}

extern "C" void kernel_launch(void* const* d_in, const int* in_sizes, int n_in,
                              void* d_out, int out_size, void* d_ws, size_t ws_size,
                              hipStream_t stream) {
  const float* x   = (const float*)d_in[0];
  const int*   ei  = (const int*)d_in[1];
  const float* W1  = (const float*)d_in[2];
  const float* b1  = (const float*)d_in[3];
  const float* g1  = (const float*)d_in[4];
  const float* be1 = (const float*)d_in[5];
  const float* Wl  = (const float*)d_in[6];
  const float* bl  = (const float*)d_in[7];
  const float* Wr  = (const float*)d_in[8];
  const float* g2  = (const float*)d_in[9];
  const float* be2 = (const float*)d_in[10];
  const int* srcp = ei;
  const int* dstp = ei + NE;

  char* w = (char*)d_ws;
  auto alloc = [&](size_t bytes) {
    char* p = w;
    w += (bytes + 255) & ~(size_t)255;
    return p;
  };
  // single zeroed zone: bar[8] | cnt[NN] | stats[1024]
  size_t zbytes = (8 + NN + 1024) * 4;
  char* zz = (char*)alloc(zbytes);
  int*   bar   = (int*)zz;
  int*   cnt   = bar + 8;
  float* stats = (float*)(cnt + NN);
  float* sums1 = stats,       *sumsq1 = stats + 128;
  float* sums2 = stats + 512, *sumsq2 = stats + 640;

  int*   csr     = (int*)alloc((size_t)NN * CAP * 4);  // 12.8 MB strided buckets
  unsigned short* xs     = (unsigned short*)alloc((size_t)NN * FIN * 2);
  unsigned short* xa     = (unsigned short*)alloc((size_t)NN * FIN * 2);
  unsigned short* hb     = (unsigned short*)alloc((size_t)NN * FHID * 2);
  unsigned*       neighb = (unsigned*)alloc((size_t)NN * FHID * 2);

  hipMemsetAsync(zz, 0, zbytes, stream);

  int nbA = NN / 16;           // 3125 sage blocks (16 nodes each)
  int nbG = (NN + 127) / 128;  // 391 MFMA blocks

  // 1: CSR build + prescale + GCN aggregation (internal grid barriers)
  fused_pre<<<768, 256, 0, stream>>>(srcp, dstp, x, cnt, csr, (ushort4*)xs, xa, bar);

  // 2: GCN GEMM K=64 + fused BN+ReLU -> bf16 hb
  gemm_bn<64, 0, true><<<nbG, 256, 0, stream>>>(
      (const short*)xa, nullptr, W1, nullptr, b1, nullptr, hb, sums1, sumsq1,
      g1, be1, bar + 2, nbG);

  // 3: SAGE mean aggregation
  sage_agg<<<nbA, 256, 0, stream>>>((const unsigned*)hb, csr, cnt, neighb);

  // 4: SAGE GEMM K=256 + fused BN+ReLU -> fp32 d_out
  gemm_bn<128, 128, false><<<nbG, 256, 0, stream>>>(
      (const short*)neighb, (const short*)hb, Wl, Wr, bl, (float*)d_out, nullptr,
      sums2, sumsq2, g2, be2, bar + 3, nbG);
}

// Round 6
// 245.078 us; speedup vs baseline: 2.2143x; 2.2143x over previous
//
#include <hip/hip_runtime.h>

// R4 lesson: device-scope grid barriers cost O(100us) on MI355X (per-block
// __threadfence => L2 writeback storms). All fusion here is block-local.

#define NN 50000
#define NE 600000
#define FIN 64
#define FHID 128
#define BN_EPS 1e-5f
#define CAP 64

typedef __attribute__((ext_vector_type(8))) short short8;
typedef __attribute__((ext_vector_type(4))) float f32x4;

// ---- bf16 helpers (finite inputs; RNE) ----
__device__ __forceinline__ unsigned short f2bf(float f) {
  unsigned u = __float_as_uint(f);
  return (unsigned short)((u + 0x7FFFu + ((u >> 16) & 1u)) >> 16);
}
__device__ __forceinline__ float bfs(unsigned short u) {
  return __uint_as_float(((unsigned)u) << 16);
}
__device__ __forceinline__ float bflo(unsigned v) { return __uint_as_float(v << 16); }
__device__ __forceinline__ float bfhi(unsigned v) { return __uint_as_float(v & 0xFFFF0000u); }
__device__ __forceinline__ unsigned pk2(float lo, float hi) {
  return (unsigned)f2bf(lo) | ((unsigned)f2bf(hi) << 16);
}

// -------- bucket CSR build + (spare blocks) pack weights to frag layout -----
// Wp layout: ((n*NKS+ks)*64+lane)*8+kk ; k=ks*32+(lane>>4)*8+kk ; col=n*16+(lane&15)
__global__ __launch_bounds__(256) void bucket_fill(
    const int* __restrict__ src, const int* __restrict__ dst,
    int* __restrict__ cnt, int* __restrict__ csr,
    const float* __restrict__ W1, const float* __restrict__ Wl,
    const float* __restrict__ Wr, short* __restrict__ Wp1,
    short* __restrict__ Wp2, int nbE4) {
  int tid = threadIdx.x;
  if ((int)blockIdx.x < nbE4) {
    int e4 = blockIdx.x * 256 + tid;  // 4 edges/thread; NE % 4 == 0
    if (e4 * 4 < NE) {
      int4 d4 = ((const int4*)dst)[e4];
      int4 s4 = ((const int4*)src)[e4];
      int p;
      p = atomicAdd(&cnt[d4.x], 1); if (p < CAP) csr[(size_t)d4.x * CAP + p] = s4.x;
      p = atomicAdd(&cnt[d4.y], 1); if (p < CAP) csr[(size_t)d4.y * CAP + p] = s4.y;
      p = atomicAdd(&cnt[d4.z], 1); if (p < CAP) csr[(size_t)d4.z * CAP + p] = s4.z;
      p = atomicAdd(&cnt[d4.w], 1); if (p < CAP) csr[(size_t)d4.w * CAP + p] = s4.w;
    }
  } else {
    int widx = (blockIdx.x - nbE4) * 256 + tid;  // 0..40959
    if (widx < 8192) {  // Wp1: NKS=2, source W1[64][128]
      int kk = widx & 7, lane = (widx >> 3) & 63, ks = (widx >> 9) & 1,
          n = widx >> 10;
      int q = lane >> 4, r = lane & 15;
      int k = ks * 32 + q * 8 + kk, col = n * 16 + r;
      Wp1[widx] = (short)f2bf(W1[k * 128 + col]);
    } else if (widx < 8192 + 32768) {  // Wp2: NKS=8, source Wl|Wr [128][128]
      int w2 = widx - 8192;
      int kk = w2 & 7, lane = (w2 >> 3) & 63, ks = (w2 >> 9) & 7, n = w2 >> 12;
      int q = lane >> 4, r = lane & 15;
      int k = ks * 32 + q * 8 + kk, col = n * 16 + r;
      float wv = (k < 128) ? Wl[k * 128 + col] : Wr[(k - 128) * 128 + col];
      Wp2[w2] = (short)f2bf(wv);
    }
  }
}

// ------- xs = dis[node]*x (fp32 -> bf16 prescale), fused bucket padding ------
__global__ __launch_bounds__(256) void scale_x(const float* __restrict__ x,
                                               const int* __restrict__ cnt,
                                               ushort4* __restrict__ xs,
                                               int* __restrict__ csr) {
  int i = blockIdx.x * 256 + threadIdx.x;  // float4 index; grid exact (800000)
  float4 v = ((const float4*)x)[i];
  int node = i >> 4;  // 16 float4 per 64-wide row
  float d = rsqrtf((float)(cnt[node] + 1));
  xs[i] = make_ushort4(f2bf(v.x * d), f2bf(v.y * d), f2bf(v.z * d), f2bf(v.w * d));
  if (i < NN) {
    int deg = min(cnt[i], CAP);
    int deg8 = (deg + 7) & ~7;
    int* cb = csr + (size_t)i * CAP;
    for (int p = deg; p < deg8; ++p) cb[p] = 0;
  }
}

__device__ __forceinline__ void gacc(float& a0, float& a1, float& a2, float& a3,
                                     ushort4 v) {
  a0 += bfs(v.x); a1 += bfs(v.y); a2 += bfs(v.z); a3 += bfs(v.w);
}

// -------- GCN block: aggregate 64 own rows -> LDS -> K=64 MFMA + stats ------
// hb output is RAW (bias only, pre-BN) bf16; BN1 applied by consumers.
__global__ __launch_bounds__(256) void gcn_block(
    const unsigned short* __restrict__ xs, const int* __restrict__ csr,
    const int* __restrict__ cnt, const short* __restrict__ Wp1,
    const float* __restrict__ b1, unsigned short* __restrict__ hb,
    float* __restrict__ sums1, float* __restrict__ sumsq1) {
  __shared__ unsigned short xaS[64][72];  // +8 pad: rows spread 4 banks apart
  __shared__ float lsum[128], lsq[128];
  int tid = threadIdx.x;
  if (tid < 128) { lsum[tid] = 0.f; lsq[tid] = 0.f; }
  int row_base = blockIdx.x * 64;
  int li = tid & 15, g = tid >> 4;
  ushort4 zv = *(const ushort4*)(xs + li * 4);  // row 0 (pad target)
  for (int it = 0; it < 4; ++it) {
    int lr = g * 4 + it;
    int node = row_base + lr;
    if (node < NN) {
      int degr = cnt[node];
      int deg = min(degr, CAP);
      int deg8 = (deg + 7) & ~7;
      float di = rsqrtf((float)(degr + 1));
      ushort4 sv = *(const ushort4*)(xs + (size_t)node * FIN + li * 4);
      float a0 = bfs(sv.x), a1 = bfs(sv.y), a2 = bfs(sv.z), a3 = bfs(sv.w);
      const int* cb = csr + (size_t)node * CAP;
      int4 sA = *(const int4*)(cb);
      int4 sB = *(const int4*)(cb + 4);
      for (int e = 0; e < deg8; e += 8) {
        int pn = min(e + 8, CAP - 8);
        int4 nA = *(const int4*)(cb + pn);
        int4 nB = *(const int4*)(cb + pn + 4);
        ushort4 v0 = *(const ushort4*)(xs + (size_t)sA.x * FIN + li * 4);
        ushort4 v1 = *(const ushort4*)(xs + (size_t)sA.y * FIN + li * 4);
        ushort4 v2 = *(const ushort4*)(xs + (size_t)sA.z * FIN + li * 4);
        ushort4 v3 = *(const ushort4*)(xs + (size_t)sA.w * FIN + li * 4);
        ushort4 v4 = *(const ushort4*)(xs + (size_t)sB.x * FIN + li * 4);
        ushort4 v5 = *(const ushort4*)(xs + (size_t)sB.y * FIN + li * 4);
        ushort4 v6 = *(const ushort4*)(xs + (size_t)sB.z * FIN + li * 4);
        ushort4 v7 = *(const ushort4*)(xs + (size_t)sB.w * FIN + li * 4);
        gacc(a0, a1, a2, a3, v0); gacc(a0, a1, a2, a3, v1);
        gacc(a0, a1, a2, a3, v2); gacc(a0, a1, a2, a3, v3);
        gacc(a0, a1, a2, a3, v4); gacc(a0, a1, a2, a3, v5);
        gacc(a0, a1, a2, a3, v6); gacc(a0, a1, a2, a3, v7);
        sA = nA; sB = nB;
      }
      float pc = (float)(deg8 - deg);
      a0 -= pc * bfs(zv.x); a1 -= pc * bfs(zv.y);
      a2 -= pc * bfs(zv.z); a3 -= pc * bfs(zv.w);
      *(ushort4*)(&xaS[lr][li * 4]) = make_ushort4(
          f2bf(di * a0), f2bf(di * a1), f2bf(di * a2), f2bf(di * a3));
    }
  }
  __syncthreads();

  int lane = tid & 63, w = tid >> 6, r = lane & 15, q = lane >> 4;
  short8 af[2];
#pragma unroll
  for (int ks = 0; ks < 2; ++ks)
    af[ks] = *(const short8*)(&xaS[w * 16 + r][ks * 32 + q * 8]);
  f32x4 acc[8];
#pragma unroll
  for (int n = 0; n < 8; ++n) acc[n] = (f32x4){0.f, 0.f, 0.f, 0.f};
#pragma unroll
  for (int ks = 0; ks < 2; ++ks)
#pragma unroll
    for (int n = 0; n < 8; ++n) {
      short8 bf = *(const short8*)(Wp1 + ((size_t)(n * 2 + ks) * 64 + lane) * 8);
      acc[n] = __builtin_amdgcn_mfma_f32_16x16x32_bf16(af[ks], bf, acc[n], 0, 0, 0);
    }

  float bias_r[8];
#pragma unroll
  for (int n = 0; n < 8; ++n) bias_r[n] = b1[n * 16 + r];
  float cs[8], cq[8];
#pragma unroll
  for (int n = 0; n < 8; ++n) { cs[n] = 0.f; cq[n] = 0.f; }
#pragma unroll
  for (int i = 0; i < 4; ++i) {
    int row = row_base + w * 16 + q * 4 + i;
    if (row < NN) {
#pragma unroll
      for (int n = 0; n < 8; ++n) {
        float v = acc[n][i] + bias_r[n];
        hb[(size_t)row * 128 + n * 16 + r] = f2bf(v);
        cs[n] += v;
        cq[n] += v * v;
      }
    }
  }
#pragma unroll
  for (int n = 0; n < 8; ++n) {
    atomicAdd(&lsum[n * 16 + r], cs[n]);
    atomicAdd(&lsq[n * 16 + r], cq[n]);
  }
  __syncthreads();
  if (tid < 128) {
    atomicAdd(&sums1[tid], lsum[tid]);
    atomicAdd(&sumsq1[tid], lsq[tid]);
  }
}

// ---- SAGE block: BN1-on-the-fly mean-agg (64 rows -> LDS) -> K=256 MFMA ----
__device__ __forceinline__ void sbn(float* a, uint4 v, const float* sc,
                                    const float* sh) {
  a[0] += fmaxf(fmaf(bflo(v.x), sc[0], sh[0]), 0.f);
  a[1] += fmaxf(fmaf(bfhi(v.x), sc[1], sh[1]), 0.f);
  a[2] += fmaxf(fmaf(bflo(v.y), sc[2], sh[2]), 0.f);
  a[3] += fmaxf(fmaf(bfhi(v.y), sc[3], sh[3]), 0.f);
  a[4] += fmaxf(fmaf(bflo(v.z), sc[4], sh[4]), 0.f);
  a[5] += fmaxf(fmaf(bfhi(v.z), sc[5], sh[5]), 0.f);
  a[6] += fmaxf(fmaf(bflo(v.w), sc[6], sh[6]), 0.f);
  a[7] += fmaxf(fmaf(bfhi(v.w), sc[7], sh[7]), 0.f);
}

__global__ __launch_bounds__(256) void sage_block(
    const unsigned short* __restrict__ hb, const int* __restrict__ csr,
    const int* __restrict__ cnt, const short* __restrict__ Wp2,
    const float* __restrict__ bl, const float* __restrict__ sums1,
    const float* __restrict__ sumsq1, const float* __restrict__ g1,
    const float* __restrict__ be1, float* __restrict__ out,
    float* __restrict__ sums2, float* __restrict__ sumsq2) {
  __shared__ unsigned short nbS[64][136];  // 272B row stride, 16B aligned
  __shared__ float scB[128], shB[128], lsum[128], lsq[128];
  int tid = threadIdx.x;
  if (tid < 128) {
    lsum[tid] = 0.f; lsq[tid] = 0.f;
    float mean = sums1[tid] * (1.0f / NN);
    float var = fmaxf(sumsq1[tid] * (1.0f / NN) - mean * mean, 0.f);
    float s = g1[tid] * rsqrtf(var + BN_EPS);
    scB[tid] = s;
    shB[tid] = be1[tid] - mean * s;
  }
  __syncthreads();

  int row_base = blockIdx.x * 64;
  int li = tid & 15, g = tid >> 4;
  const unsigned* hbu = (const unsigned*)hb;
  float sc8[8], sh8[8];
#pragma unroll
  for (int j = 0; j < 8; ++j) { sc8[j] = scB[li * 8 + j]; sh8[j] = shB[li * 8 + j]; }
  // BN'd row 0 (pad-gather target)
  float zb[8];
  {
    uint4 zr = *(const uint4*)(hbu + li * 4);
    float t[8] = {0,0,0,0,0,0,0,0};
    sbn(t, zr, sc8, sh8);
#pragma unroll
    for (int j = 0; j < 8; ++j) zb[j] = t[j];
  }
  for (int it = 0; it < 4; ++it) {
    int lr = g * 4 + it;
    int node = row_base + lr;
    if (node < NN) {
      int degr = cnt[node];
      int deg = min(degr, CAP);
      int deg8 = (deg + 7) & ~7;
      float a[8];
#pragma unroll
      for (int j = 0; j < 8; ++j) a[j] = 0.f;
      const int* cb = csr + (size_t)node * CAP;
      int4 sA = *(const int4*)(cb);
      int4 sB = *(const int4*)(cb + 4);
      for (int e = 0; e < deg8; e += 8) {
        int pn = min(e + 8, CAP - 8);
        int4 nA = *(const int4*)(cb + pn);
        int4 nB = *(const int4*)(cb + pn + 4);
        uint4 v0 = *(const uint4*)(hbu + (size_t)sA.x * 64 + li * 4);
        uint4 v1 = *(const uint4*)(hbu + (size_t)sA.y * 64 + li * 4);
        uint4 v2 = *(const uint4*)(hbu + (size_t)sA.z * 64 + li * 4);
        uint4 v3 = *(const uint4*)(hbu + (size_t)sA.w * 64 + li * 4);
        uint4 v4 = *(const uint4*)(hbu + (size_t)sB.x * 64 + li * 4);
        uint4 v5 = *(const uint4*)(hbu + (size_t)sB.y * 64 + li * 4);
        uint4 v6 = *(const uint4*)(hbu + (size_t)sB.z * 64 + li * 4);
        uint4 v7 = *(const uint4*)(hbu + (size_t)sB.w * 64 + li * 4);
        sbn(a, v0, sc8, sh8); sbn(a, v1, sc8, sh8);
        sbn(a, v2, sc8, sh8); sbn(a, v3, sc8, sh8);
        sbn(a, v4, sc8, sh8); sbn(a, v5, sc8, sh8);
        sbn(a, v6, sc8, sh8); sbn(a, v7, sc8, sh8);
        sA = nA; sB = nB;
      }
      float pc = (float)(deg8 - deg);
#pragma unroll
      for (int j = 0; j < 8; ++j) a[j] -= pc * zb[j];
      float inv = 1.0f / fmaxf((float)degr, 1.0f);
      uint4 o;
      o.x = pk2(a[0] * inv, a[1] * inv);
      o.y = pk2(a[2] * inv, a[3] * inv);
      o.z = pk2(a[4] * inv, a[5] * inv);
      o.w = pk2(a[6] * inv, a[7] * inv);
      *(uint4*)(&nbS[lr][li * 8]) = o;
    }
  }
  __syncthreads();

  int lane = tid & 63, w = tid >> 6, r = lane & 15, q = lane >> 4;
  int rowg = row_base + w * 16 + r;
  rowg = rowg < NN ? rowg : NN - 1;  // clamp: garbage rows never stored
  short8 af[8];
#pragma unroll
  for (int ks = 0; ks < 4; ++ks)
    af[ks] = *(const short8*)(&nbS[w * 16 + r][ks * 32 + q * 8]);
#pragma unroll
  for (int ks = 4; ks < 8; ++ks) {  // A2 = BN1(hb) fragments, on the fly
    int kg = (ks - 4) * 32 + q * 8;
    short8 raw = *(const short8*)((const short*)hb + (size_t)rowg * 128 + kg);
    short8 t;
#pragma unroll
    for (int j = 0; j < 8; ++j) {
      float f = fmaxf(fmaf(bfs((unsigned short)raw[j]), scB[kg + j], shB[kg + j]), 0.f);
      t[j] = (short)f2bf(f);
    }
    af[ks] = t;
  }
  f32x4 acc[8];
#pragma unroll
  for (int n = 0; n < 8; ++n) acc[n] = (f32x4){0.f, 0.f, 0.f, 0.f};
#pragma unroll
  for (int ks = 0; ks < 8; ++ks)
#pragma unroll
    for (int n = 0; n < 8; ++n) {
      short8 bf = *(const short8*)(Wp2 + ((size_t)(n * 8 + ks) * 64 + lane) * 8);
      acc[n] = __builtin_amdgcn_mfma_f32_16x16x32_bf16(af[ks], bf, acc[n], 0, 0, 0);
    }

  float bias_r[8];
#pragma unroll
  for (int n = 0; n < 8; ++n) bias_r[n] = bl[n * 16 + r];
  float cs[8], cq[8];
#pragma unroll
  for (int n = 0; n < 8; ++n) { cs[n] = 0.f; cq[n] = 0.f; }
#pragma unroll
  for (int i = 0; i < 4; ++i) {
    int row = row_base + w * 16 + q * 4 + i;
    if (row < NN) {
#pragma unroll
      for (int n = 0; n < 8; ++n) {
        float v = acc[n][i] + bias_r[n];
        out[(size_t)row * 128 + n * 16 + r] = v;
        cs[n] += v;
        cq[n] += v * v;
      }
    }
  }
#pragma unroll
  for (int n = 0; n < 8; ++n) {
    atomicAdd(&lsum[n * 16 + r], cs[n]);
    atomicAdd(&lsq[n * 16 + r], cq[n]);
  }
  __syncthreads();
  if (tid < 128) {
    atomicAdd(&sums2[tid], lsum[tid]);
    atomicAdd(&sumsq2[tid], lsq[tid]);
  }
}

// ---------------- BN finalize + apply + ReLU, fp32 in-place ------
__global__ __launch_bounds__(256) void bn_apply_f32(float* __restrict__ out,
                                                    const float* __restrict__ sums,
                                                    const float* __restrict__ sumsq,
                                                    const float* __restrict__ gamma,
                                                    const float* __restrict__ beta) {
  __shared__ float sc[128], sh[128];
  int t = threadIdx.x;
  if (t < 128) {
    float mean = sums[t] * (1.0f / NN);
    float var = fmaxf(sumsq[t] * (1.0f / NN) - mean * mean, 0.f);
    float inv = rsqrtf(var + BN_EPS);
    float s = gamma[t] * inv;
    sc[t] = s;
    sh[t] = beta[t] - mean * s;
  }
  __syncthreads();
  int i4 = blockIdx.x * 256 + t;  // float4 index; grid exact
  float4 v = ((const float4*)out)[i4];
  int f = (i4 & 31) * 4;
  v.x = fmaxf(fmaf(v.x, sc[f + 0], sh[f + 0]), 0.f);
  v.y = fmaxf(fmaf(v.y, sc[f + 1], sh[f + 1]), 0.f);
  v.z = fmaxf(fmaf(v.z, sc[f + 2], sh[f + 2]), 0.f);
  v.w = fmaxf(fmaf(v.w, sc[f + 3], sh[f + 3]), 0.f);
  ((float4*)out)[i4] = v;
}

extern "C" void kernel_launch(void* const* d_in, const int* in_sizes, int n_in,
                              void* d_out, int out_size, void* d_ws, size_t ws_size,
                              hipStream_t stream) {
  const float* x   = (const float*)d_in[0];
  const int*   ei  = (const int*)d_in[1];
  const float* W1  = (const float*)d_in[2];
  const float* b1  = (const float*)d_in[3];
  const float* g1  = (const float*)d_in[4];
  const float* be1 = (const float*)d_in[5];
  const float* Wl  = (const float*)d_in[6];
  const float* bl  = (const float*)d_in[7];
  const float* Wr  = (const float*)d_in[8];
  const float* g2  = (const float*)d_in[9];
  const float* be2 = (const float*)d_in[10];
  const int* srcp = ei;
  const int* dstp = ei + NE;

  char* w = (char*)d_ws;
  auto alloc = [&](size_t bytes) {
    char* p = w;
    w += (bytes + 255) & ~(size_t)255;
    return p;
  };
  // single zeroed zone: cnt[NN] | stats[1024]
  size_t zbytes = (NN + 1024) * 4;
  char* zz = (char*)alloc(zbytes);
  int*   cnt   = (int*)zz;
  float* stats = (float*)(cnt + NN);
  float* sums1 = stats,       *sumsq1 = stats + 128;
  float* sums2 = stats + 512, *sumsq2 = stats + 640;

  int*   csr = (int*)alloc((size_t)NN * CAP * 4);  // 12.8 MB strided buckets
  unsigned short* xs = (unsigned short*)alloc((size_t)NN * FIN * 2);
  unsigned short* hb = (unsigned short*)alloc((size_t)NN * FHID * 2);
  short* Wp1 = (short*)alloc(8192 * 2);
  short* Wp2 = (short*)alloc(32768 * 2);

  hipMemsetAsync(zz, 0, zbytes, stream);

  int nbE4 = (NE / 4 + 255) / 256;  // 586 edge blocks
  int nbW  = (8192 + 32768 + 255) / 256;  // 160 weight-pack blocks
  int nb64 = (NN + 63) / 64;        // 782 fused agg+GEMM blocks

  // 1: CSR build + weight packing (independent block ranges)
  bucket_fill<<<nbE4 + nbW, 256, 0, stream>>>(srcp, dstp, cnt, csr, W1, Wl, Wr,
                                              Wp1, Wp2, nbE4);
  // 2: prescale + bucket pad
  scale_x<<<NN * FIN / 4 / 256, 256, 0, stream>>>(x, cnt, (ushort4*)xs, csr);
  // 3: GCN agg (block-local LDS) + K=64 MFMA -> raw bf16 hb + stats1
  gcn_block<<<nb64, 256, 0, stream>>>(xs, csr, cnt, Wp1, b1, hb, sums1, sumsq1);
  // 4: SAGE mean-agg with BN1+ReLU on the fly + K=256 MFMA -> fp32 out + stats2
  sage_block<<<nb64, 256, 0, stream>>>(hb, csr, cnt, Wp2, bl, sums1, sumsq1,
                                       g1, be1, (float*)d_out, sums2, sumsq2);
  // 5: BN2 finalize + apply + ReLU
  bn_apply_f32<<<NN * FHID / 4 / 256, 256, 0, stream>>>((float*)d_out, sums2,
                                                        sumsq2, g2, be2);
}

// Round 7
// 220.372 us; speedup vs baseline: 2.4626x; 1.1121x over previous
//
#include <hip/hip_runtime.h>

// R4 lesson: device-scope grid barriers cost O(100us) on MI355X. Block-local only.
// R6 lesson: fusing gather into M=64 GEMM tiles cut grid to 782 blocks ->
// latency-bound gather starved (Occ 14%). M=16 tiles restore 3125 blocks.

#define NN 50000
#define NE 600000
#define FIN 64
#define FHID 128
#define BN_EPS 1e-5f
#define CAP 64
#define NSLOT 32

typedef __attribute__((ext_vector_type(8))) short short8;
typedef __attribute__((ext_vector_type(4))) float f32x4;

// ---- bf16 helpers (finite inputs; RNE) ----
__device__ __forceinline__ unsigned short f2bf(float f) {
  unsigned u = __float_as_uint(f);
  return (unsigned short)((u + 0x7FFFu + ((u >> 16) & 1u)) >> 16);
}
__device__ __forceinline__ float bfs(unsigned short u) {
  return __uint_as_float(((unsigned)u) << 16);
}
__device__ __forceinline__ float bflo(unsigned v) { return __uint_as_float(v << 16); }
__device__ __forceinline__ float bfhi(unsigned v) { return __uint_as_float(v & 0xFFFF0000u); }
__device__ __forceinline__ unsigned pk2(float lo, float hi) {
  return (unsigned)f2bf(lo) | ((unsigned)f2bf(hi) << 16);
}

// -------- bucket CSR build + (spare blocks) pack weights to frag layout -----
// Wp layout: ((n*NKS+ks)*64+lane)*8+kk ; k=ks*32+(lane>>4)*8+kk ; col=n*16+(lane&15)
__global__ __launch_bounds__(256) void bucket_fill(
    const int* __restrict__ src, const int* __restrict__ dst,
    int* __restrict__ cnt, int* __restrict__ csr,
    const float* __restrict__ W1, const float* __restrict__ Wl,
    const float* __restrict__ Wr, short* __restrict__ Wp1,
    short* __restrict__ Wp2, int nbE4) {
  int tid = threadIdx.x;
  if ((int)blockIdx.x < nbE4) {
    int e4 = blockIdx.x * 256 + tid;  // 4 edges/thread; NE % 4 == 0
    if (e4 * 4 < NE) {
      int4 d4 = ((const int4*)dst)[e4];
      int4 s4 = ((const int4*)src)[e4];
      int p;
      p = atomicAdd(&cnt[d4.x], 1); if (p < CAP) csr[(size_t)d4.x * CAP + p] = s4.x;
      p = atomicAdd(&cnt[d4.y], 1); if (p < CAP) csr[(size_t)d4.y * CAP + p] = s4.y;
      p = atomicAdd(&cnt[d4.z], 1); if (p < CAP) csr[(size_t)d4.z * CAP + p] = s4.z;
      p = atomicAdd(&cnt[d4.w], 1); if (p < CAP) csr[(size_t)d4.w * CAP + p] = s4.w;
    }
  } else {
    int widx = (blockIdx.x - nbE4) * 256 + tid;  // 0..40959
    if (widx < 8192) {  // Wp1: NKS=2, source W1[64][128]
      int kk = widx & 7, lane = (widx >> 3) & 63, ks = (widx >> 9) & 1,
          n = widx >> 10;
      int q = lane >> 4, r = lane & 15;
      int k = ks * 32 + q * 8 + kk, col = n * 16 + r;
      Wp1[widx] = (short)f2bf(W1[k * 128 + col]);
    } else if (widx < 8192 + 32768) {  // Wp2: NKS=8, source Wl|Wr [128][128]
      int w2 = widx - 8192;
      int kk = w2 & 7, lane = (w2 >> 3) & 63, ks = (w2 >> 9) & 7, n = w2 >> 12;
      int q = lane >> 4, r = lane & 15;
      int k = ks * 32 + q * 8 + kk, col = n * 16 + r;
      float wv = (k < 128) ? Wl[k * 128 + col] : Wr[(k - 128) * 128 + col];
      Wp2[w2] = (short)f2bf(wv);
    }
  }
}

// ------- xs = dis[node]*x (fp32 -> bf16 prescale), fused bucket padding ------
__global__ __launch_bounds__(256) void scale_x(const float* __restrict__ x,
                                               const int* __restrict__ cnt,
                                               ushort4* __restrict__ xs,
                                               int* __restrict__ csr) {
  int i = blockIdx.x * 256 + threadIdx.x;  // float4 index; grid exact (800000)
  float4 v = ((const float4*)x)[i];
  int node = i >> 4;  // 16 float4 per 64-wide row
  float d = rsqrtf((float)(cnt[node] + 1));
  xs[i] = make_ushort4(f2bf(v.x * d), f2bf(v.y * d), f2bf(v.z * d), f2bf(v.w * d));
  if (i < NN) {
    int deg = min(cnt[i], CAP);
    int deg8 = (deg + 7) & ~7;
    int* cb = csr + (size_t)i * CAP;
    for (int p = deg; p < deg8; ++p) cb[p] = 0;
  }
}

__device__ __forceinline__ void gacc(float& a0, float& a1, float& a2, float& a3,
                                     ushort4 v) {
  a0 += bfs(v.x); a1 += bfs(v.y); a2 += bfs(v.z); a3 += bfs(v.w);
}

// ---- GCN block (M=16): 1 node per 16-lane group -> LDS -> K=64 MFMA --------
// hb output RAW (bias only, pre-BN). Stats into slotted partials.
__global__ __launch_bounds__(256) void gcn_block(
    const unsigned short* __restrict__ xs, const int* __restrict__ csr,
    const int* __restrict__ cnt, const short* __restrict__ Wp1,
    const float* __restrict__ b1, unsigned short* __restrict__ hb,
    float* __restrict__ sums1s, float* __restrict__ sumsq1s) {
  __shared__ unsigned short xaS[16][72];  // 144B row stride (16B aligned)
  __shared__ float lsum[128], lsq[128];
  int tid = threadIdx.x;
  if (tid < 128) { lsum[tid] = 0.f; lsq[tid] = 0.f; }
  int row_base = blockIdx.x * 16;  // 3125*16 = 50000 exact
  int li = tid & 15, g = tid >> 4;
  int node = row_base + g;
  {
    int degr = cnt[node];
    int deg = min(degr, CAP);
    int deg8 = (deg + 7) & ~7;
    float di = rsqrtf((float)(degr + 1));
    ushort4 sv = *(const ushort4*)(xs + (size_t)node * FIN + li * 4);
    float a0 = bfs(sv.x), a1 = bfs(sv.y), a2 = bfs(sv.z), a3 = bfs(sv.w);
    ushort4 zv = *(const ushort4*)(xs + li * 4);  // row 0 (pad target)
    const int* cb = csr + (size_t)node * CAP;
    int4 sA = *(const int4*)(cb);
    int4 sB = *(const int4*)(cb + 4);
    for (int e = 0; e < deg8; e += 8) {
      int pn = min(e + 8, CAP - 8);
      int4 nA = *(const int4*)(cb + pn);
      int4 nB = *(const int4*)(cb + pn + 4);
      ushort4 v0 = *(const ushort4*)(xs + (size_t)sA.x * FIN + li * 4);
      ushort4 v1 = *(const ushort4*)(xs + (size_t)sA.y * FIN + li * 4);
      ushort4 v2 = *(const ushort4*)(xs + (size_t)sA.z * FIN + li * 4);
      ushort4 v3 = *(const ushort4*)(xs + (size_t)sA.w * FIN + li * 4);
      ushort4 v4 = *(const ushort4*)(xs + (size_t)sB.x * FIN + li * 4);
      ushort4 v5 = *(const ushort4*)(xs + (size_t)sB.y * FIN + li * 4);
      ushort4 v6 = *(const ushort4*)(xs + (size_t)sB.z * FIN + li * 4);
      ushort4 v7 = *(const ushort4*)(xs + (size_t)sB.w * FIN + li * 4);
      gacc(a0, a1, a2, a3, v0); gacc(a0, a1, a2, a3, v1);
      gacc(a0, a1, a2, a3, v2); gacc(a0, a1, a2, a3, v3);
      gacc(a0, a1, a2, a3, v4); gacc(a0, a1, a2, a3, v5);
      gacc(a0, a1, a2, a3, v6); gacc(a0, a1, a2, a3, v7);
      sA = nA; sB = nB;
    }
    float pc = (float)(deg8 - deg);
    a0 -= pc * bfs(zv.x); a1 -= pc * bfs(zv.y);
    a2 -= pc * bfs(zv.z); a3 -= pc * bfs(zv.w);
    *(ushort4*)(&xaS[g][li * 4]) = make_ushort4(
        f2bf(di * a0), f2bf(di * a1), f2bf(di * a2), f2bf(di * a3));
  }
  __syncthreads();

  int lane = tid & 63, w = tid >> 6, r = lane & 15, q = lane >> 4;
  int n0 = w * 2, n1 = w * 2 + 1;
  short8 af0 = *(const short8*)(&xaS[r][q * 8]);
  short8 af1 = *(const short8*)(&xaS[r][32 + q * 8]);
  f32x4 acc0 = (f32x4){0.f, 0.f, 0.f, 0.f}, acc1 = acc0;
  acc0 = __builtin_amdgcn_mfma_f32_16x16x32_bf16(
      af0, *(const short8*)(Wp1 + ((size_t)(n0 * 2 + 0) * 64 + lane) * 8), acc0, 0, 0, 0);
  acc1 = __builtin_amdgcn_mfma_f32_16x16x32_bf16(
      af0, *(const short8*)(Wp1 + ((size_t)(n1 * 2 + 0) * 64 + lane) * 8), acc1, 0, 0, 0);
  acc0 = __builtin_amdgcn_mfma_f32_16x16x32_bf16(
      af1, *(const short8*)(Wp1 + ((size_t)(n0 * 2 + 1) * 64 + lane) * 8), acc0, 0, 0, 0);
  acc1 = __builtin_amdgcn_mfma_f32_16x16x32_bf16(
      af1, *(const short8*)(Wp1 + ((size_t)(n1 * 2 + 1) * 64 + lane) * 8), acc1, 0, 0, 0);

  float b0 = b1[n0 * 16 + r], bb1 = b1[n1 * 16 + r];
  float cs0 = 0.f, cq0 = 0.f, cs1 = 0.f, cq1 = 0.f;
#pragma unroll
  for (int i = 0; i < 4; ++i) {
    int row = row_base + q * 4 + i;  // grid exact, always < NN
    float v0 = acc0[i] + b0;
    float v1 = acc1[i] + bb1;
    hb[(size_t)row * 128 + n0 * 16 + r] = f2bf(v0);
    hb[(size_t)row * 128 + n1 * 16 + r] = f2bf(v1);
    cs0 += v0; cq0 += v0 * v0;
    cs1 += v1; cq1 += v1 * v1;
  }
  atomicAdd(&lsum[n0 * 16 + r], cs0);
  atomicAdd(&lsq[n0 * 16 + r], cq0);
  atomicAdd(&lsum[n1 * 16 + r], cs1);
  atomicAdd(&lsq[n1 * 16 + r], cq1);
  __syncthreads();
  if (tid < 128) {
    int s = blockIdx.x & (NSLOT - 1);
    atomicAdd(&sums1s[s * 128 + tid], lsum[tid]);
    atomicAdd(&sumsq1s[s * 128 + tid], lsq[tid]);
  }
}

// ---- SAGE block (M=16): BN1-on-the-fly mean-agg -> LDS -> K=256 MFMA -------
__device__ __forceinline__ void sbn(float* a, uint4 v, const float* sc,
                                    const float* sh) {
  a[0] += fmaxf(fmaf(bflo(v.x), sc[0], sh[0]), 0.f);
  a[1] += fmaxf(fmaf(bfhi(v.x), sc[1], sh[1]), 0.f);
  a[2] += fmaxf(fmaf(bflo(v.y), sc[2], sh[2]), 0.f);
  a[3] += fmaxf(fmaf(bfhi(v.y), sc[3], sh[3]), 0.f);
  a[4] += fmaxf(fmaf(bflo(v.z), sc[4], sh[4]), 0.f);
  a[5] += fmaxf(fmaf(bfhi(v.z), sc[5], sh[5]), 0.f);
  a[6] += fmaxf(fmaf(bflo(v.w), sc[6], sh[6]), 0.f);
  a[7] += fmaxf(fmaf(bfhi(v.w), sc[7], sh[7]), 0.f);
}

__global__ __launch_bounds__(256) void sage_block(
    const unsigned short* __restrict__ hb, const int* __restrict__ csr,
    const int* __restrict__ cnt, const short* __restrict__ Wp2,
    const float* __restrict__ bl, const float* __restrict__ sums1s,
    const float* __restrict__ sumsq1s, const float* __restrict__ g1,
    const float* __restrict__ be1, float* __restrict__ out,
    float* __restrict__ sums2s, float* __restrict__ sumsq2s) {
  __shared__ unsigned short nbS[16][136];  // 272B row stride (16B aligned)
  __shared__ float scB[128], shB[128], lsum[128], lsq[128];
  int tid = threadIdx.x;
  if (tid < 128) {
    lsum[tid] = 0.f; lsq[tid] = 0.f;
    float ms = 0.f, vs = 0.f;
#pragma unroll
    for (int s = 0; s < NSLOT; ++s) {
      ms += sums1s[s * 128 + tid];
      vs += sumsq1s[s * 128 + tid];
    }
    float mean = ms * (1.0f / NN);
    float var = fmaxf(vs * (1.0f / NN) - mean * mean, 0.f);
    float sgm = g1[tid] * rsqrtf(var + BN_EPS);
    scB[tid] = sgm;
    shB[tid] = be1[tid] - mean * sgm;
  }
  __syncthreads();

  int row_base = blockIdx.x * 16;
  int li = tid & 15, g = tid >> 4;
  int node = row_base + g;
  const unsigned* hbu = (const unsigned*)hb;
  {
    float sc8[8], sh8[8];
#pragma unroll
    for (int j = 0; j < 8; ++j) { sc8[j] = scB[li * 8 + j]; sh8[j] = shB[li * 8 + j]; }
    // BN'd row 0 (pad-gather target)
    float zb[8] = {0, 0, 0, 0, 0, 0, 0, 0};
    sbn(zb, *(const uint4*)(hbu + li * 4), sc8, sh8);
    int degr = cnt[node];
    int deg = min(degr, CAP);
    int deg8 = (deg + 7) & ~7;
    float a[8];
#pragma unroll
    for (int j = 0; j < 8; ++j) a[j] = 0.f;
    const int* cb = csr + (size_t)node * CAP;
    int4 sA = *(const int4*)(cb);
    int4 sB = *(const int4*)(cb + 4);
    for (int e = 0; e < deg8; e += 8) {
      int pn = min(e + 8, CAP - 8);
      int4 nA = *(const int4*)(cb + pn);
      int4 nB = *(const int4*)(cb + pn + 4);
      uint4 v0 = *(const uint4*)(hbu + (size_t)sA.x * 64 + li * 4);
      uint4 v1 = *(const uint4*)(hbu + (size_t)sA.y * 64 + li * 4);
      uint4 v2 = *(const uint4*)(hbu + (size_t)sA.z * 64 + li * 4);
      uint4 v3 = *(const uint4*)(hbu + (size_t)sA.w * 64 + li * 4);
      uint4 v4 = *(const uint4*)(hbu + (size_t)sB.x * 64 + li * 4);
      uint4 v5 = *(const uint4*)(hbu + (size_t)sB.y * 64 + li * 4);
      uint4 v6 = *(const uint4*)(hbu + (size_t)sB.z * 64 + li * 4);
      uint4 v7 = *(const uint4*)(hbu + (size_t)sB.w * 64 + li * 4);
      sbn(a, v0, sc8, sh8); sbn(a, v1, sc8, sh8);
      sbn(a, v2, sc8, sh8); sbn(a, v3, sc8, sh8);
      sbn(a, v4, sc8, sh8); sbn(a, v5, sc8, sh8);
      sbn(a, v6, sc8, sh8); sbn(a, v7, sc8, sh8);
      sA = nA; sB = nB;
    }
    float pc = (float)(deg8 - deg);
#pragma unroll
    for (int j = 0; j < 8; ++j) a[j] -= pc * zb[j];
    float inv = 1.0f / fmaxf((float)degr, 1.0f);
    uint4 o;
    o.x = pk2(a[0] * inv, a[1] * inv);
    o.y = pk2(a[2] * inv, a[3] * inv);
    o.z = pk2(a[4] * inv, a[5] * inv);
    o.w = pk2(a[6] * inv, a[7] * inv);
    *(uint4*)(&nbS[g][li * 8]) = o;
  }
  __syncthreads();

  int lane = tid & 63, w = tid >> 6, r = lane & 15, q = lane >> 4;
  int n0 = w * 2, n1 = w * 2 + 1;
  short8 af[8];
#pragma unroll
  for (int ks = 0; ks < 4; ++ks)
    af[ks] = *(const short8*)(&nbS[r][ks * 32 + q * 8]);
  int rowg = row_base + r;  // grid exact, always < NN
#pragma unroll
  for (int ks = 4; ks < 8; ++ks) {  // A2 = BN1(hb) fragments, on the fly
    int kg = (ks - 4) * 32 + q * 8;
    short8 raw = *(const short8*)((const short*)hb + (size_t)rowg * 128 + kg);
    short8 t;
#pragma unroll
    for (int j = 0; j < 8; ++j) {
      float f = fmaxf(fmaf(bfs((unsigned short)raw[j]), scB[kg + j], shB[kg + j]), 0.f);
      t[j] = (short)f2bf(f);
    }
    af[ks] = t;
  }
  f32x4 acc0 = (f32x4){0.f, 0.f, 0.f, 0.f}, acc1 = acc0;
#pragma unroll
  for (int ks = 0; ks < 8; ++ks) {
    acc0 = __builtin_amdgcn_mfma_f32_16x16x32_bf16(
        af[ks], *(const short8*)(Wp2 + ((size_t)(n0 * 8 + ks) * 64 + lane) * 8),
        acc0, 0, 0, 0);
    acc1 = __builtin_amdgcn_mfma_f32_16x16x32_bf16(
        af[ks], *(const short8*)(Wp2 + ((size_t)(n1 * 8 + ks) * 64 + lane) * 8),
        acc1, 0, 0, 0);
  }

  float b0 = bl[n0 * 16 + r], bb1 = bl[n1 * 16 + r];
  float cs0 = 0.f, cq0 = 0.f, cs1 = 0.f, cq1 = 0.f;
#pragma unroll
  for (int i = 0; i < 4; ++i) {
    int row = row_base + q * 4 + i;
    float v0 = acc0[i] + b0;
    float v1 = acc1[i] + bb1;
    out[(size_t)row * 128 + n0 * 16 + r] = v0;
    out[(size_t)row * 128 + n1 * 16 + r] = v1;
    cs0 += v0; cq0 += v0 * v0;
    cs1 += v1; cq1 += v1 * v1;
  }
  atomicAdd(&lsum[n0 * 16 + r], cs0);
  atomicAdd(&lsq[n0 * 16 + r], cq0);
  atomicAdd(&lsum[n1 * 16 + r], cs1);
  atomicAdd(&lsq[n1 * 16 + r], cq1);
  __syncthreads();
  if (tid < 128) {
    int s = blockIdx.x & (NSLOT - 1);
    atomicAdd(&sums2s[s * 128 + tid], lsum[tid]);
    atomicAdd(&sumsq2s[s * 128 + tid], lsq[tid]);
  }
}

// ------- BN2 finalize (32-slot reduce) + apply + ReLU, fp32 in-place --------
__global__ __launch_bounds__(256) void bn_apply_f32(float* __restrict__ out,
                                                    const float* __restrict__ sums2s,
                                                    const float* __restrict__ sumsq2s,
                                                    const float* __restrict__ gamma,
                                                    const float* __restrict__ beta) {
  __shared__ float sc[128], sh[128];
  int t = threadIdx.x;
  if (t < 128) {
    float ms = 0.f, vs = 0.f;
#pragma unroll
    for (int s = 0; s < NSLOT; ++s) {
      ms += sums2s[s * 128 + t];
      vs += sumsq2s[s * 128 + t];
    }
    float mean = ms * (1.0f / NN);
    float var = fmaxf(vs * (1.0f / NN) - mean * mean, 0.f);
    float inv = rsqrtf(var + BN_EPS);
    float sgm = gamma[t] * inv;
    sc[t] = sgm;
    sh[t] = beta[t] - mean * sgm;
  }
  __syncthreads();
  int i4 = blockIdx.x * 256 + t;  // float4 index; grid exact
  float4 v = ((const float4*)out)[i4];
  int f = (i4 & 31) * 4;
  v.x = fmaxf(fmaf(v.x, sc[f + 0], sh[f + 0]), 0.f);
  v.y = fmaxf(fmaf(v.y, sc[f + 1], sh[f + 1]), 0.f);
  v.z = fmaxf(fmaf(v.z, sc[f + 2], sh[f + 2]), 0.f);
  v.w = fmaxf(fmaf(v.w, sc[f + 3], sh[f + 3]), 0.f);
  ((float4*)out)[i4] = v;
}

extern "C" void kernel_launch(void* const* d_in, const int* in_sizes, int n_in,
                              void* d_out, int out_size, void* d_ws, size_t ws_size,
                              hipStream_t stream) {
  const float* x   = (const float*)d_in[0];
  const int*   ei  = (const int*)d_in[1];
  const float* W1  = (const float*)d_in[2];
  const float* b1  = (const float*)d_in[3];
  const float* g1  = (const float*)d_in[4];
  const float* be1 = (const float*)d_in[5];
  const float* Wl  = (const float*)d_in[6];
  const float* bl  = (const float*)d_in[7];
  const float* Wr  = (const float*)d_in[8];
  const float* g2  = (const float*)d_in[9];
  const float* be2 = (const float*)d_in[10];
  const int* srcp = ei;
  const int* dstp = ei + NE;

  char* w = (char*)d_ws;
  auto alloc = [&](size_t bytes) {
    char* p = w;
    w += (bytes + 255) & ~(size_t)255;
    return p;
  };
  // single zeroed zone: cnt[NN] | slotted stats 4 x [32][128]
  size_t zbytes = ((size_t)NN + 4 * NSLOT * 128) * 4;
  char* zz = (char*)alloc(zbytes);
  int*   cnt   = (int*)zz;
  float* stats = (float*)(cnt + NN);
  float* sums1s = stats,                     *sumsq1s = stats + NSLOT * 128;
  float* sums2s = stats + 2 * NSLOT * 128,   *sumsq2s = stats + 3 * NSLOT * 128;

  int*   csr = (int*)alloc((size_t)NN * CAP * 4);  // 12.8 MB strided buckets
  unsigned short* xs = (unsigned short*)alloc((size_t)NN * FIN * 2);
  unsigned short* hb = (unsigned short*)alloc((size_t)NN * FHID * 2);
  short* Wp1 = (short*)alloc(8192 * 2);
  short* Wp2 = (short*)alloc(32768 * 2);

  hipMemsetAsync(zz, 0, zbytes, stream);

  int nbE4 = (NE / 4 + 255) / 256;        // 586 edge blocks
  int nbW  = (8192 + 32768 + 255) / 256;  // 160 weight-pack blocks
  int nb16 = NN / 16;                     // 3125 fused agg+GEMM blocks

  // 1: CSR build + weight packing (independent block ranges)
  bucket_fill<<<nbE4 + nbW, 256, 0, stream>>>(srcp, dstp, cnt, csr, W1, Wl, Wr,
                                              Wp1, Wp2, nbE4);
  // 2: prescale + bucket pad
  scale_x<<<NN * FIN / 4 / 256, 256, 0, stream>>>(x, cnt, (ushort4*)xs, csr);
  // 3: GCN agg (1 node / 16-lane group) + K=64 MFMA -> raw bf16 hb + stats1
  gcn_block<<<nb16, 256, 0, stream>>>(xs, csr, cnt, Wp1, b1, hb, sums1s, sumsq1s);
  // 4: SAGE mean-agg with BN1+ReLU on the fly + K=256 MFMA -> fp32 out + stats2
  sage_block<<<nb16, 256, 0, stream>>>(hb, csr, cnt, Wp2, bl, sums1s, sumsq1s,
                                       g1, be1, (float*)d_out, sums2s, sumsq2s);
  // 5: BN2 finalize (slot reduce) + apply + ReLU
  bn_apply_f32<<<NN * FHID / 4 / 256, 256, 0, stream>>>((float*)d_out, sums2s,
                                                        sumsq2s, g2, be2);
}

// Round 8
// 215.010 us; speedup vs baseline: 2.5240x; 1.0249x over previous
//
#include <hip/hip_runtime.h>

// R4 lesson: device-scope grid barriers cost O(100us) on MI355X. Block-local only.
// R6 lesson: gather needs >=3000 blocks; M=16 fused tiles keep 3125.
// R7 lesson: BN-on-the-fly in the gather doubles hot-loop VALU (69us vs <42us
// plain); per-block slot-reduce prologues add 50-100MB L2 reads. BN1 is a
// separate streaming pass; bn kernels grid-stride at 512 blocks.

#define NN 50000
#define NE 600000
#define FIN 64
#define FHID 128
#define BN_EPS 1e-5f
#define CAP 64
#define NSLOT 32

typedef __attribute__((ext_vector_type(8))) short short8;
typedef __attribute__((ext_vector_type(4))) float f32x4;

// ---- bf16 helpers (finite inputs; RNE) ----
__device__ __forceinline__ unsigned short f2bf(float f) {
  unsigned u = __float_as_uint(f);
  return (unsigned short)((u + 0x7FFFu + ((u >> 16) & 1u)) >> 16);
}
__device__ __forceinline__ float bfs(unsigned short u) {
  return __uint_as_float(((unsigned)u) << 16);
}
__device__ __forceinline__ float bflo(unsigned v) { return __uint_as_float(v << 16); }
__device__ __forceinline__ float bfhi(unsigned v) { return __uint_as_float(v & 0xFFFF0000u); }
__device__ __forceinline__ unsigned pk2(float lo, float hi) {
  return (unsigned)f2bf(lo) | ((unsigned)f2bf(hi) << 16);
}

// -------- bucket CSR build + (spare blocks) pack weights to frag layout -----
// Wp layout: ((n*NKS+ks)*64+lane)*8+kk ; k=ks*32+(lane>>4)*8+kk ; col=n*16+(lane&15)
__global__ __launch_bounds__(256) void bucket_fill(
    const int* __restrict__ src, const int* __restrict__ dst,
    int* __restrict__ cnt, int* __restrict__ csr,
    const float* __restrict__ W1, const float* __restrict__ Wl,
    const float* __restrict__ Wr, short* __restrict__ Wp1,
    short* __restrict__ Wp2, int nbE4) {
  int tid = threadIdx.x;
  if ((int)blockIdx.x < nbE4) {
    int e4 = blockIdx.x * 256 + tid;  // 4 edges/thread; NE % 4 == 0
    if (e4 * 4 < NE) {
      int4 d4 = ((const int4*)dst)[e4];
      int4 s4 = ((const int4*)src)[e4];
      int p;
      p = atomicAdd(&cnt[d4.x], 1); if (p < CAP) csr[(size_t)d4.x * CAP + p] = s4.x;
      p = atomicAdd(&cnt[d4.y], 1); if (p < CAP) csr[(size_t)d4.y * CAP + p] = s4.y;
      p = atomicAdd(&cnt[d4.z], 1); if (p < CAP) csr[(size_t)d4.z * CAP + p] = s4.z;
      p = atomicAdd(&cnt[d4.w], 1); if (p < CAP) csr[(size_t)d4.w * CAP + p] = s4.w;
    }
  } else {
    int widx = (blockIdx.x - nbE4) * 256 + tid;  // 0..40959
    if (widx < 8192) {  // Wp1: NKS=2, source W1[64][128]
      int kk = widx & 7, lane = (widx >> 3) & 63, ks = (widx >> 9) & 1,
          n = widx >> 10;
      int q = lane >> 4, r = lane & 15;
      int k = ks * 32 + q * 8 + kk, col = n * 16 + r;
      Wp1[widx] = (short)f2bf(W1[k * 128 + col]);
    } else if (widx < 8192 + 32768) {  // Wp2: NKS=8, source Wl|Wr [128][128]
      int w2 = widx - 8192;
      int kk = w2 & 7, lane = (w2 >> 3) & 63, ks = (w2 >> 9) & 7, n = w2 >> 12;
      int q = lane >> 4, r = lane & 15;
      int k = ks * 32 + q * 8 + kk, col = n * 16 + r;
      float wv = (k < 128) ? Wl[k * 128 + col] : Wr[(k - 128) * 128 + col];
      Wp2[w2] = (short)f2bf(wv);
    }
  }
}

// ------- xs = dis[node]*x (fp32 -> bf16 prescale), fused bucket padding ------
__global__ __launch_bounds__(256) void scale_x(const float* __restrict__ x,
                                               const int* __restrict__ cnt,
                                               ushort4* __restrict__ xs,
                                               int* __restrict__ csr) {
  int i = blockIdx.x * 256 + threadIdx.x;  // float4 index; grid exact (800000)
  float4 v = ((const float4*)x)[i];
  int node = i >> 4;  // 16 float4 per 64-wide row
  float d = rsqrtf((float)(cnt[node] + 1));
  xs[i] = make_ushort4(f2bf(v.x * d), f2bf(v.y * d), f2bf(v.z * d), f2bf(v.w * d));
  if (i < NN) {
    int deg = min(cnt[i], CAP);
    int deg8 = (deg + 7) & ~7;
    int* cb = csr + (size_t)i * CAP;
    for (int p = deg; p < deg8; ++p) cb[p] = 0;
  }
}

__device__ __forceinline__ void gacc(float& a0, float& a1, float& a2, float& a3,
                                     ushort4 v) {
  a0 += bfs(v.x); a1 += bfs(v.y); a2 += bfs(v.z); a3 += bfs(v.w);
}

// ---- GCN block (M=16): 1 node per 16-lane group -> LDS -> K=64 MFMA --------
// hb output RAW (bias only, pre-BN). Stats into slotted partials.
__global__ __launch_bounds__(256) void gcn_block(
    const unsigned short* __restrict__ xs, const int* __restrict__ csr,
    const int* __restrict__ cnt, const short* __restrict__ Wp1,
    const float* __restrict__ b1, unsigned short* __restrict__ hb,
    float* __restrict__ sums1s, float* __restrict__ sumsq1s) {
  __shared__ unsigned short xaS[16][72];  // 144B row stride (16B aligned)
  __shared__ float lsum[128], lsq[128];
  int tid = threadIdx.x;
  if (tid < 128) { lsum[tid] = 0.f; lsq[tid] = 0.f; }
  int row_base = blockIdx.x * 16;  // 3125*16 = 50000 exact
  int li = tid & 15, g = tid >> 4;
  int node = row_base + g;
  {
    int degr = cnt[node];
    int deg = min(degr, CAP);
    int deg8 = (deg + 7) & ~7;
    float di = rsqrtf((float)(degr + 1));
    ushort4 sv = *(const ushort4*)(xs + (size_t)node * FIN + li * 4);
    float a0 = bfs(sv.x), a1 = bfs(sv.y), a2 = bfs(sv.z), a3 = bfs(sv.w);
    ushort4 zv = *(const ushort4*)(xs + li * 4);  // row 0 (pad target)
    const int* cb = csr + (size_t)node * CAP;
    int4 sA = *(const int4*)(cb);
    int4 sB = *(const int4*)(cb + 4);
    for (int e = 0; e < deg8; e += 8) {
      int pn = min(e + 8, CAP - 8);
      int4 nA = *(const int4*)(cb + pn);
      int4 nB = *(const int4*)(cb + pn + 4);
      ushort4 v0 = *(const ushort4*)(xs + (size_t)sA.x * FIN + li * 4);
      ushort4 v1 = *(const ushort4*)(xs + (size_t)sA.y * FIN + li * 4);
      ushort4 v2 = *(const ushort4*)(xs + (size_t)sA.z * FIN + li * 4);
      ushort4 v3 = *(const ushort4*)(xs + (size_t)sA.w * FIN + li * 4);
      ushort4 v4 = *(const ushort4*)(xs + (size_t)sB.x * FIN + li * 4);
      ushort4 v5 = *(const ushort4*)(xs + (size_t)sB.y * FIN + li * 4);
      ushort4 v6 = *(const ushort4*)(xs + (size_t)sB.z * FIN + li * 4);
      ushort4 v7 = *(const ushort4*)(xs + (size_t)sB.w * FIN + li * 4);
      gacc(a0, a1, a2, a3, v0); gacc(a0, a1, a2, a3, v1);
      gacc(a0, a1, a2, a3, v2); gacc(a0, a1, a2, a3, v3);
      gacc(a0, a1, a2, a3, v4); gacc(a0, a1, a2, a3, v5);
      gacc(a0, a1, a2, a3, v6); gacc(a0, a1, a2, a3, v7);
      sA = nA; sB = nB;
    }
    float pc = (float)(deg8 - deg);
    a0 -= pc * bfs(zv.x); a1 -= pc * bfs(zv.y);
    a2 -= pc * bfs(zv.z); a3 -= pc * bfs(zv.w);
    *(ushort4*)(&xaS[g][li * 4]) = make_ushort4(
        f2bf(di * a0), f2bf(di * a1), f2bf(di * a2), f2bf(di * a3));
  }
  __syncthreads();

  int lane = tid & 63, w = tid >> 6, r = lane & 15, q = lane >> 4;
  int n0 = w * 2, n1 = w * 2 + 1;
  short8 af0 = *(const short8*)(&xaS[r][q * 8]);
  short8 af1 = *(const short8*)(&xaS[r][32 + q * 8]);
  f32x4 acc0 = (f32x4){0.f, 0.f, 0.f, 0.f}, acc1 = acc0;
  acc0 = __builtin_amdgcn_mfma_f32_16x16x32_bf16(
      af0, *(const short8*)(Wp1 + ((size_t)(n0 * 2 + 0) * 64 + lane) * 8), acc0, 0, 0, 0);
  acc1 = __builtin_amdgcn_mfma_f32_16x16x32_bf16(
      af0, *(const short8*)(Wp1 + ((size_t)(n1 * 2 + 0) * 64 + lane) * 8), acc1, 0, 0, 0);
  acc0 = __builtin_amdgcn_mfma_f32_16x16x32_bf16(
      af1, *(const short8*)(Wp1 + ((size_t)(n0 * 2 + 1) * 64 + lane) * 8), acc0, 0, 0, 0);
  acc1 = __builtin_amdgcn_mfma_f32_16x16x32_bf16(
      af1, *(const short8*)(Wp1 + ((size_t)(n1 * 2 + 1) * 64 + lane) * 8), acc1, 0, 0, 0);

  float b0 = b1[n0 * 16 + r], bb1 = b1[n1 * 16 + r];
  float cs0 = 0.f, cq0 = 0.f, cs1 = 0.f, cq1 = 0.f;
#pragma unroll
  for (int i = 0; i < 4; ++i) {
    int row = row_base + q * 4 + i;  // grid exact, always < NN
    float v0 = acc0[i] + b0;
    float v1 = acc1[i] + bb1;
    hb[(size_t)row * 128 + n0 * 16 + r] = f2bf(v0);
    hb[(size_t)row * 128 + n1 * 16 + r] = f2bf(v1);
    cs0 += v0; cq0 += v0 * v0;
    cs1 += v1; cq1 += v1 * v1;
  }
  atomicAdd(&lsum[n0 * 16 + r], cs0);
  atomicAdd(&lsq[n0 * 16 + r], cq0);
  atomicAdd(&lsum[n1 * 16 + r], cs1);
  atomicAdd(&lsq[n1 * 16 + r], cq1);
  __syncthreads();
  if (tid < 128) {
    int s = blockIdx.x & (NSLOT - 1);
    atomicAdd(&sums1s[s * 128 + tid], lsum[tid]);
    atomicAdd(&sumsq1s[s * 128 + tid], lsq[tid]);
  }
}

// ---- BN1 finalize (slot reduce once) + apply + ReLU, bf16 in-place ---------
// grid-stride at 512 blocks: slot-reduce prologue runs 512x, not 6250x.
__global__ __launch_bounds__(256) void bn_slot_apply_bf(
    unsigned* __restrict__ hb, const float* __restrict__ sums1s,
    const float* __restrict__ sumsq1s, const float* __restrict__ gamma,
    const float* __restrict__ beta) {
  __shared__ float sc[128], sh[128];
  int t = threadIdx.x;
  if (t < 128) {
    float ms = 0.f, vs = 0.f;
#pragma unroll
    for (int s = 0; s < NSLOT; ++s) {
      ms += sums1s[s * 128 + t];
      vs += sumsq1s[s * 128 + t];
    }
    float mean = ms * (1.0f / NN);
    float var = fmaxf(vs * (1.0f / NN) - mean * mean, 0.f);
    float sgm = gamma[t] * rsqrtf(var + BN_EPS);
    sc[t] = sgm;
    sh[t] = beta[t] - mean * sgm;
  }
  __syncthreads();
  for (int i = blockIdx.x * 256 + t; i < NN * FHID / 4; i += gridDim.x * 256) {
    uint2 v = ((uint2*)hb)[i];
    int c = (i & 31) * 4;
    float f0 = fmaxf(fmaf(bflo(v.x), sc[c + 0], sh[c + 0]), 0.f);
    float f1 = fmaxf(fmaf(bfhi(v.x), sc[c + 1], sh[c + 1]), 0.f);
    float f2 = fmaxf(fmaf(bflo(v.y), sc[c + 2], sh[c + 2]), 0.f);
    float f3 = fmaxf(fmaf(bfhi(v.y), sc[c + 3], sh[c + 3]), 0.f);
    v.x = pk2(f0, f1);
    v.y = pk2(f2, f3);
    ((uint2*)hb)[i] = v;
  }
}

// ---- SAGE block (M=16): plain-add mean-agg of BN'd hb -> LDS -> K=256 MFMA -
__device__ __forceinline__ void sacc(float* a, uint4 v) {
  a[0] += bflo(v.x); a[1] += bfhi(v.x);
  a[2] += bflo(v.y); a[3] += bfhi(v.y);
  a[4] += bflo(v.z); a[5] += bfhi(v.z);
  a[6] += bflo(v.w); a[7] += bfhi(v.w);
}

__global__ __launch_bounds__(256) void sage_block(
    const unsigned short* __restrict__ hb, const int* __restrict__ csr,
    const int* __restrict__ cnt, const short* __restrict__ Wp2,
    const float* __restrict__ bl, float* __restrict__ out,
    float* __restrict__ sums2s, float* __restrict__ sumsq2s) {
  __shared__ unsigned short nbS[16][136];  // 272B row stride (16B aligned)
  __shared__ float lsum[128], lsq[128];
  int tid = threadIdx.x;
  if (tid < 128) { lsum[tid] = 0.f; lsq[tid] = 0.f; }
  int row_base = blockIdx.x * 16;
  int li = tid & 15, g = tid >> 4;
  int node = row_base + g;
  const unsigned* hbu = (const unsigned*)hb;
  {
    int degr = cnt[node];
    int deg = min(degr, CAP);
    int deg8 = (deg + 7) & ~7;
    float a[8];
#pragma unroll
    for (int j = 0; j < 8; ++j) a[j] = 0.f;
    uint4 zv = *(const uint4*)(hbu + li * 4);  // BN'd row 0 (pad target)
    const int* cb = csr + (size_t)node * CAP;
    int4 sA = *(const int4*)(cb);
    int4 sB = *(const int4*)(cb + 4);
    for (int e = 0; e < deg8; e += 8) {
      int pn = min(e + 8, CAP - 8);
      int4 nA = *(const int4*)(cb + pn);
      int4 nB = *(const int4*)(cb + pn + 4);
      uint4 v0 = *(const uint4*)(hbu + (size_t)sA.x * 64 + li * 4);
      uint4 v1 = *(const uint4*)(hbu + (size_t)sA.y * 64 + li * 4);
      uint4 v2 = *(const uint4*)(hbu + (size_t)sA.z * 64 + li * 4);
      uint4 v3 = *(const uint4*)(hbu + (size_t)sA.w * 64 + li * 4);
      uint4 v4 = *(const uint4*)(hbu + (size_t)sB.x * 64 + li * 4);
      uint4 v5 = *(const uint4*)(hbu + (size_t)sB.y * 64 + li * 4);
      uint4 v6 = *(const uint4*)(hbu + (size_t)sB.z * 64 + li * 4);
      uint4 v7 = *(const uint4*)(hbu + (size_t)sB.w * 64 + li * 4);
      sacc(a, v0); sacc(a, v1); sacc(a, v2); sacc(a, v3);
      sacc(a, v4); sacc(a, v5); sacc(a, v6); sacc(a, v7);
      sA = nA; sB = nB;
    }
    float pc = (float)(deg8 - deg);
    a[0] -= pc * bflo(zv.x); a[1] -= pc * bfhi(zv.x);
    a[2] -= pc * bflo(zv.y); a[3] -= pc * bfhi(zv.y);
    a[4] -= pc * bflo(zv.z); a[5] -= pc * bfhi(zv.z);
    a[6] -= pc * bflo(zv.w); a[7] -= pc * bfhi(zv.w);
    float inv = 1.0f / fmaxf((float)degr, 1.0f);
    uint4 o;
    o.x = pk2(a[0] * inv, a[1] * inv);
    o.y = pk2(a[2] * inv, a[3] * inv);
    o.z = pk2(a[4] * inv, a[5] * inv);
    o.w = pk2(a[6] * inv, a[7] * inv);
    *(uint4*)(&nbS[g][li * 8]) = o;
  }
  __syncthreads();

  int lane = tid & 63, w = tid >> 6, r = lane & 15, q = lane >> 4;
  int n0 = w * 2, n1 = w * 2 + 1;
  short8 af[8];
#pragma unroll
  for (int ks = 0; ks < 4; ++ks)
    af[ks] = *(const short8*)(&nbS[r][ks * 32 + q * 8]);
  int rowg = row_base + r;  // grid exact, always < NN
#pragma unroll
  for (int ks = 4; ks < 8; ++ks) {  // A2 = BN'd hb, direct read
    int kg = (ks - 4) * 32 + q * 8;
    af[ks] = *(const short8*)((const short*)hb + (size_t)rowg * 128 + kg);
  }
  f32x4 acc0 = (f32x4){0.f, 0.f, 0.f, 0.f}, acc1 = acc0;
#pragma unroll
  for (int ks = 0; ks < 8; ++ks) {
    acc0 = __builtin_amdgcn_mfma_f32_16x16x32_bf16(
        af[ks], *(const short8*)(Wp2 + ((size_t)(n0 * 8 + ks) * 64 + lane) * 8),
        acc0, 0, 0, 0);
    acc1 = __builtin_amdgcn_mfma_f32_16x16x32_bf16(
        af[ks], *(const short8*)(Wp2 + ((size_t)(n1 * 8 + ks) * 64 + lane) * 8),
        acc1, 0, 0, 0);
  }

  float b0 = bl[n0 * 16 + r], bb1 = bl[n1 * 16 + r];
  float cs0 = 0.f, cq0 = 0.f, cs1 = 0.f, cq1 = 0.f;
#pragma unroll
  for (int i = 0; i < 4; ++i) {
    int row = row_base + q * 4 + i;
    float v0 = acc0[i] + b0;
    float v1 = acc1[i] + bb1;
    out[(size_t)row * 128 + n0 * 16 + r] = v0;
    out[(size_t)row * 128 + n1 * 16 + r] = v1;
    cs0 += v0; cq0 += v0 * v0;
    cs1 += v1; cq1 += v1 * v1;
  }
  atomicAdd(&lsum[n0 * 16 + r], cs0);
  atomicAdd(&lsq[n0 * 16 + r], cq0);
  atomicAdd(&lsum[n1 * 16 + r], cs1);
  atomicAdd(&lsq[n1 * 16 + r], cq1);
  __syncthreads();
  if (tid < 128) {
    int s = blockIdx.x & (NSLOT - 1);
    atomicAdd(&sums2s[s * 128 + tid], lsum[tid]);
    atomicAdd(&sumsq2s[s * 128 + tid], lsq[tid]);
  }
}

// ---- BN2 finalize (slot reduce once) + apply + ReLU, fp32 in-place ---------
__global__ __launch_bounds__(256) void bn_slot_apply_f32(
    float* __restrict__ out, const float* __restrict__ sums2s,
    const float* __restrict__ sumsq2s, const float* __restrict__ gamma,
    const float* __restrict__ beta) {
  __shared__ float sc[128], sh[128];
  int t = threadIdx.x;
  if (t < 128) {
    float ms = 0.f, vs = 0.f;
#pragma unroll
    for (int s = 0; s < NSLOT; ++s) {
      ms += sums2s[s * 128 + t];
      vs += sumsq2s[s * 128 + t];
    }
    float mean = ms * (1.0f / NN);
    float var = fmaxf(vs * (1.0f / NN) - mean * mean, 0.f);
    float sgm = gamma[t] * rsqrtf(var + BN_EPS);
    sc[t] = sgm;
    sh[t] = beta[t] - mean * sgm;
  }
  __syncthreads();
  for (int i4 = blockIdx.x * 256 + t; i4 < NN * FHID / 4; i4 += gridDim.x * 256) {
    float4 v = ((const float4*)out)[i4];
    int f = (i4 & 31) * 4;
    v.x = fmaxf(fmaf(v.x, sc[f + 0], sh[f + 0]), 0.f);
    v.y = fmaxf(fmaf(v.y, sc[f + 1], sh[f + 1]), 0.f);
    v.z = fmaxf(fmaf(v.z, sc[f + 2], sh[f + 2]), 0.f);
    v.w = fmaxf(fmaf(v.w, sc[f + 3], sh[f + 3]), 0.f);
    ((float4*)out)[i4] = v;
  }
}

extern "C" void kernel_launch(void* const* d_in, const int* in_sizes, int n_in,
                              void* d_out, int out_size, void* d_ws, size_t ws_size,
                              hipStream_t stream) {
  const float* x   = (const float*)d_in[0];
  const int*   ei  = (const int*)d_in[1];
  const float* W1  = (const float*)d_in[2];
  const float* b1  = (const float*)d_in[3];
  const float* g1  = (const float*)d_in[4];
  const float* be1 = (const float*)d_in[5];
  const float* Wl  = (const float*)d_in[6];
  const float* bl  = (const float*)d_in[7];
  const float* Wr  = (const float*)d_in[8];
  const float* g2  = (const float*)d_in[9];
  const float* be2 = (const float*)d_in[10];
  const int* srcp = ei;
  const int* dstp = ei + NE;

  char* w = (char*)d_ws;
  auto alloc = [&](size_t bytes) {
    char* p = w;
    w += (bytes + 255) & ~(size_t)255;
    return p;
  };
  // single zeroed zone: cnt[NN] | slotted stats 4 x [32][128]
  size_t zbytes = ((size_t)NN + 4 * NSLOT * 128) * 4;
  char* zz = (char*)alloc(zbytes);
  int*   cnt   = (int*)zz;
  float* stats = (float*)(cnt + NN);
  float* sums1s = stats,                     *sumsq1s = stats + NSLOT * 128;
  float* sums2s = stats + 2 * NSLOT * 128,   *sumsq2s = stats + 3 * NSLOT * 128;

  int*   csr = (int*)alloc((size_t)NN * CAP * 4);  // 12.8 MB strided buckets
  unsigned short* xs = (unsigned short*)alloc((size_t)NN * FIN * 2);
  unsigned short* hb = (unsigned short*)alloc((size_t)NN * FHID * 2);
  short* Wp1 = (short*)alloc(8192 * 2);
  short* Wp2 = (short*)alloc(32768 * 2);

  hipMemsetAsync(zz, 0, zbytes, stream);

  int nbE4 = (NE / 4 + 255) / 256;        // 586 edge blocks
  int nbW  = (8192 + 32768 + 255) / 256;  // 160 weight-pack blocks
  int nb16 = NN / 16;                     // 3125 fused agg+GEMM blocks

  // 1: CSR build + weight packing (independent block ranges)
  bucket_fill<<<nbE4 + nbW, 256, 0, stream>>>(srcp, dstp, cnt, csr, W1, Wl, Wr,
                                              Wp1, Wp2, nbE4);
  // 2: prescale + bucket pad
  scale_x<<<NN * FIN / 4 / 256, 256, 0, stream>>>(x, cnt, (ushort4*)xs, csr);
  // 3: GCN agg (1 node / 16-lane group) + K=64 MFMA -> raw bf16 hb + stats1
  gcn_block<<<nb16, 256, 0, stream>>>(xs, csr, cnt, Wp1, b1, hb, sums1s, sumsq1s);
  // 4: BN1 finalize + apply + ReLU in place on hb
  bn_slot_apply_bf<<<512, 256, 0, stream>>>((unsigned*)hb, sums1s, sumsq1s, g1, be1);
  // 5: SAGE plain-add mean-agg + K=256 MFMA -> fp32 out + stats2
  sage_block<<<nb16, 256, 0, stream>>>(hb, csr, cnt, Wp2, bl, (float*)d_out,
                                       sums2s, sumsq2s);
  // 6: BN2 finalize + apply + ReLU
  bn_slot_apply_f32<<<512, 256, 0, stream>>>((float*)d_out, sums2s, sumsq2s, g2, be2);
}